// Round 1
// baseline (356.475 us; speedup 1.0000x reference)
//
#include <hip/hip_runtime.h>
#include <hip/hip_fp16.h>

#define NFEAT 64
#define SCAN_CHUNK 2048   // 256 threads x 8

typedef _Float16 half8 __attribute__((ext_vector_type(8)));
typedef float f32x4 __attribute__((ext_vector_type(4)));

// ---------------- async global->LDS helper (16B per lane, wave-uniform LDS base) ---
__device__ __forceinline__ void gll16(const float* g, float* l) {
    __builtin_amdgcn_global_load_lds(
        (const __attribute__((address_space(1))) unsigned int*)g,
        (__attribute__((address_space(3))) unsigned int*)l, 16, 0, 0);
}

__device__ __forceinline__ __half2 bch(unsigned int u) {
    return __builtin_bit_cast(__half2, u);
}

// ---------------- W transpose+convert: Wt[n][k] = fp16(W[k][n]) ----------------
__global__ void k_cvtW(const float* __restrict__ W, __half* __restrict__ Wt, int K) {
    int idx = blockIdx.x * 256 + threadIdx.x;
    if (idx >= 64 * K) return;
    int n = idx / K;
    int k = idx % K;
    Wt[idx] = __float2half(W[(size_t)k * NFEAT + n]);
}

// ---------------- FUSED: MFMA GEMM  +  degree-count/rank -----------------------
// CNT: odd blocks run the count path (1:1 interleave, 1563 count blocks cover E),
// hiding atomic write-through latency under the MFMA blocks.
// GEMM: BM=64 tile, W read per-lane from global (L1-resident 32KB) instead of LDS.
// LDS = 16KB/block -> ~5 blocks/CU resident (vs 2 at the old 65KB), the fix for
// the latency-bound profile (Occupancy 17.6%, all pipes idle).
template<int K, bool SCALE, bool CNT>
__global__ __launch_bounds__(256) void k_gemm_x(
    const float* __restrict__ A, const __half* __restrict__ Wt,
    const float* __restrict__ dinv, __half* __restrict__ H, int M,
    const int* __restrict__ eiDst, int* __restrict__ counts,
    int* __restrict__ rank, int E)
{
    int tid = threadIdx.x;
    int gemmIdx;
    if (CNT) {
        int bid = blockIdx.x;
        if (bid & 1) {
            // ---- count path: 4 edges/thread, batched atomics ----
            int t = (((bid >> 1) * 256) + tid) * 4;
            if (t + 3 < E) {
                int4 d = *(const int4*)(eiDst + t);
                int r0 = atomicAdd(&counts[d.x], 1);
                int r1 = atomicAdd(&counts[d.y], 1);
                int r2 = atomicAdd(&counts[d.z], 1);
                int r3 = atomicAdd(&counts[d.w], 1);
                *(int4*)(rank + t) = make_int4(r0, r1, r2, r3);
            } else {
                for (int e = t; e < E; ++e)
                    rank[e] = atomicAdd(&counts[eiDst[e]], 1);
            }
            return;
        }
        gemmIdx = bid >> 1;
    } else {
        gemmIdx = blockIdx.x;
    }

    const int BM = 64, BK = 32;
    __shared__ float As[2 * BM * BK];     // 16 KB, [buf][chunk-swizzled], chunk=4 floats

    int w = tid >> 6, lane = tid & 63;
    int q = lane >> 4, n16 = lane & 15;
    int m0 = gemmIdx * BM;

    auto stage = [&](int k0, int buf) {
#pragma unroll
        for (int rep = 0; rep < 2; ++rep) {
            int cb = (w * 2 + rep) * 64;          // chunk base (wave-uniform), 0..511
            int s = cb + lane;                    // chunk index
            int m = s >> 3;                       // tile row 0..63
            int kk = (s & 7) ^ (m & 7);           // XOR swizzle
            int row = m0 + m; if (row > M - 1) row = M - 1;  // clamp, never stored
            gll16(A + (size_t)row * K + k0 + kk * 4,
                  &As[buf * (BM * BK) + cb * 4]);
        }
    };

    stage(0, 0);   // async

    f32x4 acc[4];
#pragma unroll
    for (int nt = 0; nt < 4; ++nt) acc[nt] = (f32x4)(0.f);

    // per-lane W base: row n16 (+nt*16), cols q*8; L1-cached (whole W = 64*K*2 B)
    const __half* wp = Wt + (size_t)n16 * K + q * 8;

    const int T = K / BK;
    for (int kt = 0; kt < T; ++kt) {
        __syncthreads();                      // tile kt deposited
        if (kt + 1 < T) stage((kt + 1) * BK, (kt + 1) & 1);
        const float* As_ = &As[(kt & 1) * (BM * BK)];

        int ml = w * 16 + n16;
        int e0 = (2 * q) ^ (ml & 7);
        int e1 = (2 * q + 1) ^ (ml & 7);
        float4 f0 = *(const float4*)&As_[(ml * 8 + e0) * 4];
        float4 f1 = *(const float4*)&As_[(ml * 8 + e1) * 4];
        float fv[8] = {f0.x, f0.y, f0.z, f0.w, f1.x, f1.y, f1.z, f1.w};
        half8 ahi, alo;
#pragma unroll
        for (int j = 0; j < 8; ++j) {
            _Float16 hi = (_Float16)fv[j];
            ahi[j] = hi;
            alo[j] = (_Float16)(fv[j] - (float)hi);
        }
#pragma unroll
        for (int nt = 0; nt < 4; ++nt) {
            uint4 u = *(const uint4*)(wp + (size_t)(nt * 16) * K + kt * BK);
            half8 b = __builtin_bit_cast(half8, u);
            acc[nt] = __builtin_amdgcn_mfma_f32_16x16x32_f16(ahi, b, acc[nt], 0, 0, 0);
            acc[nt] = __builtin_amdgcn_mfma_f32_16x16x32_f16(alo, b, acc[nt], 0, 0, 0);
        }
        __syncthreads();
    }

    // epilogue: D[row = q*4+reg][col = n16]
#pragma unroll
    for (int reg = 0; reg < 4; ++reg) {
        int row = m0 + w * 16 + q * 4 + reg;
        if (row < M) {
            float di = SCALE ? dinv[row] : 1.0f;
#pragma unroll
            for (int nt = 0; nt < 4; ++nt)
                H[(size_t)row * NFEAT + nt * 16 + n16] =
                    __float2half(di * acc[nt][reg]);
        }
    }
}

// ---------------- FUSED: scan phase A + dinv ----------------------------------
__global__ __launch_bounds__(256) void k_dinv_scan(
    const int* __restrict__ counts, int* __restrict__ bsums,
    float* __restrict__ dinv, int n, int nbScan)
{
    __shared__ int red[256];
    int bid = blockIdx.x;
    int tid = threadIdx.x;
    if (bid < nbScan) {
        int base = bid * SCAN_CHUNK + tid * 8;
        int s = 0;
#pragma unroll
        for (int i = 0; i < 8; ++i) {
            int idx = base + i;
            s += (idx < n) ? counts[idx] : 0;
        }
        red[tid] = s;
        __syncthreads();
        for (int off = 128; off; off >>= 1) {
            if (tid < off) red[tid] += red[tid + off];
            __syncthreads();
        }
        if (tid == 0) bsums[bid] = red[0];
    } else {
        int i = (bid - nbScan) * 256 + tid;
        if (i < n) dinv[i] = rsqrtf((float)(counts[i] + 1));  // +1 self-loop
    }
}

__global__ void k_scan_sums(int* bsums, int nb) {
    __shared__ int ts[64];
    int tid = threadIdx.x;
    if (tid < 64) ts[tid] = (tid < nb) ? bsums[tid] : 0;
    __syncthreads();
    if (tid == 0) {
        int run = 0;
        for (int i = 0; i < nb; ++i) { int t = ts[i]; ts[i] = run; run += t; }
    }
    __syncthreads();
    if (tid < nb) bsums[tid] = ts[tid];
}

__global__ __launch_bounds__(256) void k_scan_final(const int* __restrict__ counts,
                                                    const int* __restrict__ bsums,
                                                    int* __restrict__ rowptr, int n) {
    __shared__ int ts[256];
    int tid = threadIdx.x;
    int base0 = blockIdx.x * SCAN_CHUNK + tid * 8;
    int v[8], c[8];
    int s = 0;
#pragma unroll
    for (int i = 0; i < 8; ++i) {
        int idx = base0 + i;
        c[i] = (idx < n) ? counts[idx] : 0;
        v[i] = s;
        s += c[i];
    }
    ts[tid] = s;
    __syncthreads();
    for (int off = 1; off < 256; off <<= 1) {
        int t = (tid >= off) ? ts[tid - off] : 0;
        __syncthreads();
        if (tid >= off) ts[tid] += t;
        __syncthreads();
    }
    int texcl = ts[tid] - s;
    int base = bsums[blockIdx.x] + texcl;
#pragma unroll
    for (int i = 0; i < 8; ++i) {
        int idx = base0 + i;
        if (idx < n) {
            int val = base + v[i];
            rowptr[idx] = val;
            if (idx == n - 1) rowptr[n] = val + c[i];
        }
    }
}

// ---------------- FUSED: CSR placement + deferred h *= dinv --------------------
__global__ __launch_bounds__(256) void k_build_scale(
    const int* __restrict__ ei, const int* __restrict__ rank,
    const int* __restrict__ rowptr, int* __restrict__ col, int E,
    __half* __restrict__ A, const float* __restrict__ dinv, int N, int gE)
{
    int bid = blockIdx.x;
    if (bid < gE) {
        int e = bid * 256 + threadIdx.x;
        if (e >= E) return;
        int src = ei[e];
        int dst = ei[(size_t)E + e];
        col[rowptr[dst] + rank[e]] = src;
    } else {
        int i = (bid - gE) * 256 + threadIdx.x;   // uint4 index (8 halves)
        if (i >= N * 8) return;
        float di = dinv[i >> 3];
        uint4* p = (uint4*)A + i;
        uint4 u = *p;
        auto sc = [&](unsigned int x) {
            float2 f = __half22float2(bch(x));
            return __builtin_bit_cast(unsigned int,
                   __float22half2_rn(make_float2(f.x * di, f.y * di)));
        };
        u.x = sc(u.x); u.y = sc(u.y); u.z = sc(u.z); u.w = sc(u.w);
        *p = u;
    }
}

// ---------------- CSR gather-aggregate: 1 slot = 1 row ------------------------
template<bool FC>
__global__ __launch_bounds__(256) void k_aggr(
    const __half* __restrict__ h, const int* __restrict__ rowptr,
    const int* __restrict__ col, const float* __restrict__ dinv,
    const float* __restrict__ bias, const float* __restrict__ Wfc,
    const float* __restrict__ bfc, float* __restrict__ out, int n)
{
    __shared__ float Wl[NFEAT * 11 + 11];
    int tid = threadIdx.x;
    if (FC) {
        for (int i = tid; i < NFEAT * 11; i += 256) Wl[i] = Wfc[i];
        if (tid < 11) Wl[NFEAT * 11 + tid] = bfc[tid];
        __syncthreads();
    }
    int lane = tid & 63;
    int li = lane & 7;
    int fi = li << 3;
    int r = blockIdx.x * 32 + ((tid >> 6) << 3) + (lane >> 3);
    bool valid = r < n;

    int beg = 0, end = 0;
    if (valid) { beg = rowptr[r]; end = rowptr[r + 1]; }

    const __half* hp = h + fi;
    auto ld = [&](int src) { return *(const uint4*)(hp + (size_t)src * NFEAT); };

    float a0 = 0.f, a1 = 0.f, a2 = 0.f, a3 = 0.f,
          a4 = 0.f, a5 = 0.f, a6 = 0.f, a7 = 0.f;
    auto addu = [&](uint4 u) {
        float2 f0 = __half22float2(bch(u.x));
        float2 f1 = __half22float2(bch(u.y));
        float2 f2 = __half22float2(bch(u.z));
        float2 f3 = __half22float2(bch(u.w));
        a0 += f0.x; a1 += f0.y; a2 += f1.x; a3 += f1.y;
        a4 += f2.x; a5 += f2.y; a6 += f3.x; a7 += f3.y;
    };

    if (valid) addu(ld(r));
    int j = beg;
    for (; j + 1 < end; j += 2) {
        uint4 u0 = ld(col[j]);
        uint4 u1 = ld(col[j + 1]);
        uint4 s;
        s.x = __builtin_bit_cast(unsigned int, __hadd2(bch(u0.x), bch(u1.x)));
        s.y = __builtin_bit_cast(unsigned int, __hadd2(bch(u0.y), bch(u1.y)));
        s.z = __builtin_bit_cast(unsigned int, __hadd2(bch(u0.z), bch(u1.z)));
        s.w = __builtin_bit_cast(unsigned int, __hadd2(bch(u0.w), bch(u1.w)));
        addu(s);
    }
    if (j < end) addu(ld(col[j]));

    if (!valid) return;
    float di = dinv[r];
    float t0 = fmaxf(bias[fi + 0] + di * a0, 0.f);
    float t1 = fmaxf(bias[fi + 1] + di * a1, 0.f);
    float t2 = fmaxf(bias[fi + 2] + di * a2, 0.f);
    float t3 = fmaxf(bias[fi + 3] + di * a3, 0.f);
    float t4 = fmaxf(bias[fi + 4] + di * a4, 0.f);
    float t5 = fmaxf(bias[fi + 5] + di * a5, 0.f);
    float t6 = fmaxf(bias[fi + 6] + di * a6, 0.f);
    float t7 = fmaxf(bias[fi + 7] + di * a7, 0.f);

    if (!FC) {
        float4 lo = make_float4(t0, t1, t2, t3);
        float4 hi = make_float4(t4, t5, t6, t7);
        float* op = out + (size_t)r * NFEAT + fi;
        *(float4*)op = lo;
        *(float4*)(op + 4) = hi;
    } else {
#pragma unroll
        for (int c = 0; c < 11; ++c) {
            const float* wc = &Wl[fi * 11 + c];
            float p = t0 * wc[0] + t1 * wc[11] + t2 * wc[22] + t3 * wc[33]
                    + t4 * wc[44] + t5 * wc[55] + t6 * wc[66] + t7 * wc[77];
            p += __shfl_xor(p, 1, 64);
            p += __shfl_xor(p, 2, 64);
            p += __shfl_xor(p, 4, 64);
            if (li == 0) out[(size_t)r * 11 + c] = p + Wl[NFEAT * 11 + c];
        }
    }
}

extern "C" void kernel_launch(void* const* d_in, const int* in_sizes, int n_in,
                              void* d_out, int out_size, void* d_ws, size_t ws_size,
                              hipStream_t stream) {
    const float* x   = (const float*)d_in[0];
    const int*   ei  = (const int*)d_in[1];
    const float* W1  = (const float*)d_in[2];
    const float* b1  = (const float*)d_in[3];
    const float* W2  = (const float*)d_in[4];
    const float* b2  = (const float*)d_in[5];
    const float* Wfc = (const float*)d_in[6];
    const float* bfc = (const float*)d_in[7];
    float* out = (float*)d_out;

    const int Fin = 256;
    int N = in_sizes[0] / Fin;      // 100000
    int E = in_sizes[1] / 2;        // 1600000

    char* ws = (char*)d_ws;
    size_t off = 0;
    auto alloc = [&](size_t bytes) { void* p = ws + off; off = (off + bytes + 255) & ~(size_t)255; return p; };
    int*    counts = (int*)   alloc((size_t)N * 4);
    int*    rowptr = (int*)   alloc((size_t)(N + 1) * 4);
    float*  dinv   = (float*) alloc((size_t)N * 4);
    int*    bsums  = (int*)   alloc(64 * 4);
    int*    rank   = (int*)   alloc((size_t)E * 4);
    int*    col    = (int*)   alloc((size_t)E * 4);
    __half* Wt1    = (__half*)alloc((size_t)64 * 256 * 2);
    __half* Wt2    = (__half*)alloc((size_t)64 * 64 * 2);
    __half* A      = (__half*)alloc((size_t)N * NFEAT * 2);  // h buffer (fp16)
    float*  B      = (float*) alloc((size_t)N * NFEAT * 4);  // relu(out1) buffer

    int gE = (E + 255) / 256;       // 6250
    int gb = (N + 63) / 64;         // 1563 (BM=64 tiles)
    int gA = (N + 31) / 32;         // 3125
    int gS = (N * 8 + 255) / 256;   // 3125 (scale, uint4 granules)
    int nb = (N + SCAN_CHUNK - 1) / SCAN_CHUNK;   // 49 <= 64
    int gN = (N + 255) / 256;       // 391

    hipMemsetAsync(counts, 0, (size_t)N * 4, stream);
    k_cvtW<<<(64 * 256 + 255) / 256, 256, 0, stream>>>(W1, Wt1, 256);
    k_cvtW<<<(64 * 64 + 255) / 256, 256, 0, stream>>>(W2, Wt2, 64);

    // FUSED: gemm1 (unscaled) + degree count/rank, 1:1 block interleave
    // (1563 count blocks x 1024 edges >= E)
    k_gemm_x<256, false, true><<<gb * 2, 256, 0, stream>>>(
        x, Wt1, nullptr, A, N, ei + E, counts, rank, E);

    // scan phase A + dinv
    k_dinv_scan<<<nb + gN, 256, 0, stream>>>(counts, bsums, dinv, N, nb);
    k_scan_sums<<<1, 64, 0, stream>>>(bsums, nb);
    k_scan_final<<<nb, 256, 0, stream>>>(counts, bsums, rowptr, N);

    // FUSED: CSR placement + deferred h1 *= dinv
    k_build_scale<<<gE + gS, 256, 0, stream>>>(ei, rank, rowptr, col, E, A, dinv, N, gE);

    // layer 1 aggregation: B = relu(b1 + dinv*(h1[r]+sum h1[col]))
    k_aggr<false><<<gA, 256, 0, stream>>>(A, rowptr, col, dinv, b1, nullptr, nullptr, B, N);

    // layer 2: h2 = fp16(dinv*(B@W2)); fused aggr+relu+FC -> out
    k_gemm_x<64, true, false><<<gb, 256, 0, stream>>>(
        B, Wt2, dinv, A, N, nullptr, nullptr, nullptr, 0);
    k_aggr<true><<<gA, 256, 0, stream>>>(A, rowptr, col, dinv, b2, Wfc, bfc, out, N);
}